// Round 10
// baseline (167.206 us; speedup 1.0000x reference)
//
#include <hip/hip_runtime.h>
#include <math.h>
#include <stdint.h>

// Problem constants (static per reference)
#define BB 8
#define NN 384
#define FF 64
#define TT 192
#define NSRC 383          // T + TAU - 1
#define NSINK 192
#define SS 5
#define NEDGE 441600      // B * 55200
#define BN (BB * NN)      // 3072
#define TILE_E 128        // edges per block
#define NBLKE (NEDGE / TILE_E)    // 3450 exactly
#define OUTV ((BB * NN * NN) / 4) // 294912 float4 to zero

typedef float f32x2 __attribute__((ext_vector_type(2)));

#if defined(__has_builtin) && __has_builtin(__builtin_elementwise_fma)
#define PKFMA(a, b, c) __builtin_elementwise_fma((a), (b), (c))
#else
#define PKFMA(a, b, c) ((a) * (b) + (c))
#endif

__device__ __forceinline__ float sel8(const float* s, int i) {
  return (i & 4) ? ((i & 2) ? ((i & 1) ? s[7] : s[6]) : ((i & 1) ? s[5] : s[4]))
                 : ((i & 2) ? ((i & 1) ? s[3] : s[2]) : ((i & 1) ? s[1] : s[0]));
}

// ---------------- prep: node projections (4 rows/block) + weight folding ----------------
__global__ __launch_bounds__(64) void prep_all(
    const float* __restrict__ nodes, const float* __restrict__ w1,
    const float* __restrict__ b1,
    const float* __restrict__ w2, const float* __restrict__ b2,
    const float* __restrict__ g1, const float* __restrict__ be1,
    const float* __restrict__ g2, const float* __restrict__ be2,
    const float* __restrict__ w3, const float* __restrict__ b3,
    float* __restrict__ A, float* __restrict__ Bv,
    float* __restrict__ W2kj, float* __restrict__ wcol,
    float* __restrict__ cb, float* __restrict__ gw,
    float* __restrict__ cwsgw) {
  const int blk = blockIdx.x;
  const int k = threadIdx.x;
  if (blk < BN / 4) {
    const int bn0 = blk * 4;
    __shared__ float nd[4][FF];
#pragma unroll
    for (int i = 0; i < 4; ++i) nd[i][k] = nodes[(bn0 + i) * FF + k];
    __syncthreads();
    const float bk = b1[k];
    float a0 = bk, a1 = bk, a2 = bk, a3 = bk;
    float q0 = 0.f, q1 = 0.f, q2 = 0.f, q3 = 0.f;
#pragma unroll 8
    for (int f = 0; f < FF; ++f) {
      const float wt = w1[f * FF + k];
      const float wb = w1[(FF + f) * FF + k];
      const float n0 = nd[0][f], n1 = nd[1][f], n2 = nd[2][f], n3 = nd[3][f];
      a0 = fmaf(n0, wt, a0); a1 = fmaf(n1, wt, a1);
      a2 = fmaf(n2, wt, a2); a3 = fmaf(n3, wt, a3);
      q0 = fmaf(n0, wb, q0); q1 = fmaf(n1, wb, q1);
      q2 = fmaf(n2, wb, q2); q3 = fmaf(n3, wb, q3);
    }
    A[(bn0 + 0) * FF + k] = a0;  Bv[(bn0 + 0) * FF + k] = q0;
    A[(bn0 + 1) * FF + k] = a1;  Bv[(bn0 + 1) * FF + k] = q1;
    A[(bn0 + 2) * FF + k] = a2;  Bv[(bn0 + 2) * FF + k] = q2;
    A[(bn0 + 3) * FF + k] = a3;  Bv[(bn0 + 3) * FF + k] = q3;
  } else {
    const int j = k;
    float cbj = b2[j];
    float wc = 0.f;
    for (int kk = 0; kk < FF; ++kk) {
      const float wraw = w2[kk * FF + j];
      const float w = g1[kk] * wraw;
      W2kj[kk * FF + j] = w;
      wc += w;
      cbj = fmaf(be1[kk], wraw, cbj);
    }
    wcol[j] = wc;
    cb[j] = cbj;
    const float gwj = g2[j] * w3[j];
    gw[j] = gwj;
    __shared__ float sA[FF], sB[FF];
    sA[j] = gwj;
    sB[j] = be2[j] * w3[j];
    __syncthreads();
    if (j == 0) {
      float a = 0.f, bq = 0.f;
      for (int i = 0; i < FF; ++i) { a += sA[i]; bq += sB[i]; }
      cwsgw[0] = b3[0] + bq;
      cwsgw[1] = a;
    }
  }
}

// ---------------- main: 256 thr / 128 edges per block; wave = (slab, j-half) ----------------
// wave (slab = w>>1, jh = w&1) computes edges [64*slab, 64*slab+64) x j [32*jh, 32*jh+32).
// lane: ep4 = lane>>3 -> 8 edges (4 f32x2 pairs), j4 = lane&7 -> 4 j.  32 accumulators.
__global__ __launch_bounds__(256, 3) void edge_mlp(
    const float* __restrict__ A, const float* __restrict__ Bv,
    const float* __restrict__ W2kj, const float* __restrict__ wcolg,
    const float* __restrict__ cbg, const float* __restrict__ gwg,
    const float* __restrict__ cwsgw,
    const int* __restrict__ bidx, const int* __restrict__ ridx,
    const int* __restrict__ cidx, float* __restrict__ L,
    float4* __restrict__ outv) {
  __shared__ float Wl[FF][FF];        // 16 KB, k-major
  __shared__ float X[2][FF][64];      // 32 KB: [slab][k][edge]
  __shared__ float St[TILE_E][2];     // 1 KB: {mu, rstd}
  __shared__ float Sp[2][TILE_E][4];  // 4 KB: per-j-half partial {s1,s2,s3,-}

  const int tid = threadIdx.x;       // 0..255

  // fused zeroing of the output grid (3450*256 >= OUTV)
  const int gtid = blockIdx.x * 256 + tid;
  if (gtid < OUTV) outv[gtid] = make_float4(0.f, 0.f, 0.f, 0.f);

  // ---- stage W2 (4096 floats = 1024 float4, 4/thread, coalesced) ----
  {
    const float4* src = (const float4*)W2kj;
    float4* dst = (float4*)&Wl[0][0];
#pragma unroll
    for (int i = 0; i < 4; ++i) dst[tid + 256 * i] = src[tid + 256 * i];
  }

  // ---- phase 1 (r4-verified pattern): 2 threads/edge, X + LN stats ----
  const int el = tid >> 1;        // local edge 0..127
  const int kh = tid & 1;         // k-half
  const int ge = blockIdx.x * TILE_E + el;
  const int b = bidx[ge], r = ridx[ge], c = cidx[ge];
  {
    const float4* pa = (const float4*)(A + (b * NN + r) * FF + kh * 32);
    const float4* pb = (const float4*)(Bv + (b * NN + c) * FF + kh * 32);
    const int slab1 = el >> 6, e64 = el & 63;
    float s = 0.f, q = 0.f;
#pragma unroll
    for (int i = 0; i < 8; ++i) {
      const float4 av = pa[i];
      const float4 bv = pb[i];
      const float x0 = fmaxf(av.x + bv.x, 0.f);
      const float x1 = fmaxf(av.y + bv.y, 0.f);
      const float x2 = fmaxf(av.z + bv.z, 0.f);
      const float x3 = fmaxf(av.w + bv.w, 0.f);
      const int kb = kh * 32 + 4 * i;
      X[slab1][kb + 0][e64] = x0;
      X[slab1][kb + 1][e64] = x1;
      X[slab1][kb + 2][e64] = x2;
      X[slab1][kb + 3][e64] = x3;
      s += x0; s += x1; s += x2; s += x3;
      q = fmaf(x0, x0, q); q = fmaf(x1, x1, q);
      q = fmaf(x2, x2, q); q = fmaf(x3, x3, q);
    }
    s += __shfl_xor(s, 1, 64);
    q += __shfl_xor(q, 1, 64);
    const float mu = s * (1.f / FF);
    const float rstd = 1.f / sqrtf(q * (1.f / FF) - mu * mu + 1e-5f);
    St[el][kh] = kh ? rstd : mu;
  }

  __syncthreads();   // W staging + X slabs + St

  // ---- phase 2: k-loop, 8 edges (4 pairs) x 4 j per lane ----
  const int wave = tid >> 6;
  const int lane = tid & 63;
  const int slab = wave >> 1;
  const int jh = wave & 1;
  const int ep4 = lane >> 3;      // edge octet index
  const int j4 = lane & 7;
  const int j0 = 32 * jh + 4 * j4;

  f32x2 t2[4][4];   // [edge-pair][j]
#pragma unroll
  for (int p = 0; p < 4; ++p)
#pragma unroll
    for (int j = 0; j < 4; ++j) t2[p][j] = (f32x2){0.f, 0.f};

  const float* xrow = &X[slab][0][8 * ep4];   // +64 per k
  const float* wrow = &Wl[0][j0];             // +64 per k
#pragma unroll 4
  for (int k = 0; k < FF; ++k) {
    const float4 xA = *(const float4*)xrow;
    const float4 xB = *(const float4*)(xrow + 4);
    xrow += 64;
    const float4 wv = *(const float4*)wrow;
    wrow += 64;
    f32x2 xp[4];
    xp[0].x = xA.x; xp[0].y = xA.y;
    xp[1].x = xA.z; xp[1].y = xA.w;
    xp[2].x = xB.x; xp[2].y = xB.y;
    xp[3].x = xB.z; xp[3].y = xB.w;
    f32x2 ws[4];
    ws[0].x = wv.x; ws[0].y = wv.x;
    ws[1].x = wv.y; ws[1].y = wv.y;
    ws[2].x = wv.z; ws[2].y = wv.z;
    ws[3].x = wv.w; ws[3].y = wv.w;
#pragma unroll
    for (int p = 0; p < 4; ++p)
#pragma unroll
      for (int j = 0; j < 4; ++j)
        t2[p][j] = PKFMA(xp[p], ws[j], t2[p][j]);
  }

  // ---- epilogue: LN1-affine + relu + LN2 partials over this wave's 4 j ----
  const float4 wc4 = *(const float4*)(wcolg + j0);
  const float4 cb4 = *(const float4*)(cbg + j0);
  const float4 gw4 = *(const float4*)(gwg + j0);
  const float wc[4] = {wc4.x, wc4.y, wc4.z, wc4.w};
  const float cbv[4] = {cb4.x, cb4.y, cb4.z, cb4.w};
  const float gwv[4] = {gw4.x, gw4.y, gw4.z, gw4.w};

  float s1[8], s2[8], s3[8];
#pragma unroll
  for (int ei = 0; ei < 8; ++ei) {
    const int eloc = slab * 64 + 8 * ep4 + ei;
    const float2 st = *(const float2*)&St[eloc][0];   // {mu, rstd}
    const float m = st.x, rs = st.y;
    const int p = ei >> 1;
    float a1 = 0.f, a2 = 0.f, a3 = 0.f;
#pragma unroll
    for (int j = 0; j < 4; ++j) {
      const float tv = (ei & 1) ? t2[p][j].y : t2[p][j].x;
      const float pre = fmaf(rs, fmaf(-m, wc[j], tv), cbv[j]);
      const float tr = fmaxf(pre, 0.f);
      a1 += tr;
      a2 = fmaf(tr, tr, a2);
      a3 = fmaf(tr, gwv[j], a3);
    }
    s1[ei] = a1; s2[ei] = a2; s3[ei] = a3;
  }
  // butterfly over j4 lanes (bits 0..2): full 32-j sums per (wave, edge)
#pragma unroll
  for (int off = 1; off <= 4; off <<= 1) {
#pragma unroll
    for (int ei = 0; ei < 8; ++ei) {
      s1[ei] += __shfl_xor(s1[ei], off, 64);
      s2[ei] += __shfl_xor(s2[ei], off, 64);
      s3[ei] += __shfl_xor(s3[ei], off, 64);
    }
  }
  // lane stores partials for edge (8*ep4 + j4) of its slab
  {
    const int eloc = slab * 64 + 8 * ep4 + j4;
    Sp[jh][eloc][0] = sel8(s1, j4);
    Sp[jh][eloc][1] = sel8(s2, j4);
    Sp[jh][eloc][2] = sel8(s3, j4);
  }

  __syncthreads();

  // ---- finalize: even thread of each edge merges the two j-halves ----
  if (kh == 0) {
    const float S1 = Sp[0][el][0] + Sp[1][el][0];
    const float S2 = Sp[0][el][1] + Sp[1][el][1];
    const float S3 = Sp[0][el][2] + Sp[1][el][2];
    const float cw = cwsgw[0], sgw = cwsgw[1];
    const float mu2 = S1 * (1.f / FF);
    const float var2 = S2 * (1.f / FF) - mu2 * mu2;
    const float rstd2 = 1.f / sqrtf(var2 + 1e-5f);
    const float logit = fmaf(rstd2, fmaf(-mu2, sgw, S3), cw);
    L[(b * NSINK + (r - TT)) * NSRC + c] = logit;
  }
}

// ---------------- argmax over sources + scatter ones ----------------
__global__ __launch_bounds__(256) void argmax_scatter(
    const float* __restrict__ L, const float* __restrict__ gum,
    float* __restrict__ out) {
  const int task = blockIdx.x * 4 + (threadIdx.x >> 6);  // ((s*B+b)*192+row)
  const int lane = threadIdx.x & 63;
  const int row = task % NSINK;
  const int sb = task / NSINK;   // s*B + b
  const int b = sb & 7;
  const int r = row + TT;

  const float* __restrict__ lrow = L + (b * NSINK + row) * NSRC;
  const float* __restrict__ grow = gum + task * NSRC;

  float bv = -INFINITY;
  int bi = 0;
  for (int c = lane; c < r; c += 64) {
    const float v = lrow[c] + grow[c];
    if (v > bv) { bv = v; bi = c; }   // strict > keeps smallest index per lane
  }
#pragma unroll
  for (int off = 32; off > 0; off >>= 1) {
    const float ov = __shfl_xor(bv, off, 64);
    const int oi = __shfl_xor(bi, off, 64);
    if (ov > bv || (ov == bv && oi < bi)) { bv = ov; bi = oi; }
  }
  if (lane == 0) out[(b * NN + r) * NN + bi] = 1.0f;
}

extern "C" void kernel_launch(void* const* d_in, const int* in_sizes, int n_in,
                              void* d_out, int out_size, void* d_ws, size_t ws_size,
                              hipStream_t stream) {
  const float* nodes = (const float*)d_in[0];
  const float* w1 = (const float*)d_in[1];
  const float* b1 = (const float*)d_in[2];
  const float* g1 = (const float*)d_in[3];
  const float* be1 = (const float*)d_in[4];
  const float* w2 = (const float*)d_in[5];
  const float* b2 = (const float*)d_in[6];
  const float* g2 = (const float*)d_in[7];
  const float* be2 = (const float*)d_in[8];
  const float* w3 = (const float*)d_in[9];
  const float* b3 = (const float*)d_in[10];
  const float* gum = (const float*)d_in[11];
  const int* bidx = (const int*)d_in[12];
  const int* ridx = (const int*)d_in[13];
  const int* cidx = (const int*)d_in[14];
  float* out = (float*)d_out;

  // workspace layout (floats)
  float* ws = (float*)d_ws;
  float* A = ws;                       // 8*384*64 = 196608
  float* Bv = A + BN * FF;             // 196608
  float* W2kj = Bv + BN * FF;          // 4096
  float* wcol = W2kj + FF * FF;        // 64
  float* cb = wcol + FF;               // 64
  float* gw = cb + FF;                 // 64
  float* cwsgw = gw + FF;              // 2
  float* L = ws + 397520;              // 8*192*383 = 588288
  (void)ws_size; (void)n_in; (void)in_sizes; (void)out_size;

  hipLaunchKernelGGL(prep_all, dim3(BN / 4 + 1), dim3(64), 0, stream,
                     nodes, w1, b1, w2, b2, g1, be1, g2, be2, w3, b3,
                     A, Bv, W2kj, wcol, cb, gw, cwsgw);
  hipLaunchKernelGGL(edge_mlp, dim3(NBLKE), dim3(256), 0, stream,
                     A, Bv, W2kj, wcol, cb, gw, cwsgw, bidx, ridx, cidx, L,
                     (float4*)out);
  hipLaunchKernelGGL(argmax_scatter, dim3((SS * BB * NSINK) / 4), dim3(256), 0, stream,
                     L, gum, out);
}

// Round 11
// 162.353 us; speedup vs baseline: 1.0299x; 1.0299x over previous
//
#include <hip/hip_runtime.h>
#include <math.h>
#include <stdint.h>

// Problem constants (static per reference)
#define BB 8
#define NN 384
#define FF 64
#define TT 192
#define NSRC 383          // T + TAU - 1
#define NSINK 192
#define SS 5
#define NEDGE 441600      // B * 55200
#define BN (BB * NN)      // 3072
#define TILE_E 256        // edges per block (1 lane <-> 1 edge)
#define NBLKE (NEDGE / TILE_E)    // 1725 exactly
#define OUTV ((BB * NN * NN) / 4) // 294912 float4 to zero

typedef float f32x2 __attribute__((ext_vector_type(2)));

#if defined(__has_builtin) && __has_builtin(__builtin_elementwise_fma)
#define PKFMA(a, b, c) __builtin_elementwise_fma((a), (b), (c))
#else
#define PKFMA(a, b, c) ((a) * (b) + (c))
#endif

#define CONST_AS __attribute__((address_space(4)))
typedef const CONST_AS float cfloat;

// ---------------- prep: node projections (4 rows/block) + weight folding ----------------
__global__ __launch_bounds__(64) void prep_all(
    const float* __restrict__ nodes, const float* __restrict__ w1,
    const float* __restrict__ b1,
    const float* __restrict__ w2, const float* __restrict__ b2,
    const float* __restrict__ g1, const float* __restrict__ be1,
    const float* __restrict__ g2, const float* __restrict__ be2,
    const float* __restrict__ w3, const float* __restrict__ b3,
    float* __restrict__ A, float* __restrict__ Bv,
    float* __restrict__ W2kj, float* __restrict__ wcol,
    float* __restrict__ cb, float* __restrict__ gw,
    float* __restrict__ cwsgw) {
  const int blk = blockIdx.x;
  const int k = threadIdx.x;
  if (blk < BN / 4) {
    const int bn0 = blk * 4;
    __shared__ float nd[4][FF];
#pragma unroll
    for (int i = 0; i < 4; ++i) nd[i][k] = nodes[(bn0 + i) * FF + k];
    __syncthreads();
    const float bk = b1[k];
    float a0 = bk, a1 = bk, a2 = bk, a3 = bk;
    float q0 = 0.f, q1 = 0.f, q2 = 0.f, q3 = 0.f;
#pragma unroll 8
    for (int f = 0; f < FF; ++f) {
      const float wt = w1[f * FF + k];
      const float wb = w1[(FF + f) * FF + k];
      const float n0 = nd[0][f], n1 = nd[1][f], n2 = nd[2][f], n3 = nd[3][f];
      a0 = fmaf(n0, wt, a0); a1 = fmaf(n1, wt, a1);
      a2 = fmaf(n2, wt, a2); a3 = fmaf(n3, wt, a3);
      q0 = fmaf(n0, wb, q0); q1 = fmaf(n1, wb, q1);
      q2 = fmaf(n2, wb, q2); q3 = fmaf(n3, wb, q3);
    }
    A[(bn0 + 0) * FF + k] = a0;  Bv[(bn0 + 0) * FF + k] = q0;
    A[(bn0 + 1) * FF + k] = a1;  Bv[(bn0 + 1) * FF + k] = q1;
    A[(bn0 + 2) * FF + k] = a2;  Bv[(bn0 + 2) * FF + k] = q2;
    A[(bn0 + 3) * FF + k] = a3;  Bv[(bn0 + 3) * FF + k] = q3;
  } else {
    const int j = k;
    float cbj = b2[j];
    float wc = 0.f;
    for (int kk = 0; kk < FF; ++kk) {
      const float wraw = w2[kk * FF + j];
      const float w = g1[kk] * wraw;
      W2kj[kk * FF + j] = w;
      wc += w;
      cbj = fmaf(be1[kk], wraw, cbj);
    }
    wcol[j] = wc;
    cb[j] = cbj;
    const float gwj = g2[j] * w3[j];
    gw[j] = gwj;
    __shared__ float sA[FF], sB[FF];
    sA[j] = gwj;
    sB[j] = be2[j] * w3[j];
    __syncthreads();
    if (j == 0) {
      float a = 0.f, bq = 0.f;
      for (int i = 0; i < FF; ++i) { a += sA[i]; bq += sB[i]; }
      cwsgw[0] = b3[0] + bq;
      cwsgw[1] = a;
    }
  }
}

// ---------------- main: lane-autonomous MLP. x in VGPRs, W2 via scalar pipe ----------------
// 1 lane <-> 1 edge. No LDS, no barriers, no cross-lane ops.
// k-loop: t2[32] (f32x2, j-pairs) += splat(x[k]) * w[k][2jp..2jp+1] (uniform s_load).
__global__ __launch_bounds__(256, 3) void edge_mlp(
    const float* __restrict__ A, const float* __restrict__ Bv,
    const float* __restrict__ W2kjg, const float* __restrict__ wcolg,
    const float* __restrict__ cbg, const float* __restrict__ gwg,
    const float* __restrict__ cwsgwg,
    const int* __restrict__ bidx, const int* __restrict__ ridx,
    const int* __restrict__ cidx, float* __restrict__ L,
    float4* __restrict__ outv) {
  const int tid = threadIdx.x;
  const int gtid = blockIdx.x * 256 + tid;

  // fused zeroing of the output grid (1725*256 = 441600 >= OUTV)
  if (gtid < OUTV) outv[gtid] = make_float4(0.f, 0.f, 0.f, 0.f);

  // uniform tables -> scalar pipe
  cfloat* W = (cfloat*)(uintptr_t)W2kjg;        // [k][j], k-major
  cfloat* wcol = (cfloat*)(uintptr_t)wcolg;
  cfloat* cbc = (cfloat*)(uintptr_t)cbg;
  cfloat* gwc = (cfloat*)(uintptr_t)gwg;
  cfloat* cwsgw = (cfloat*)(uintptr_t)cwsgwg;

  const int ge = gtid;                           // lane's edge
  const int b = bidx[ge], r = ridx[ge], c = cidx[ge];
  const float4* __restrict__ pa = (const float4*)(A + (b * NN + r) * FF);
  const float4* __restrict__ pb = (const float4*)(Bv + (b * NN + c) * FF);

  f32x2 t2[32];
#pragma unroll
  for (int jp = 0; jp < 32; ++jp) t2[jp] = (f32x2){0.f, 0.f};

  float s = 0.f, q = 0.f;

  // 4 chunks of 16 k: gather+relu into registers, then FMA against scalar W rows
#pragma unroll
  for (int c4 = 0; c4 < 4; ++c4) {
    float xch[16];
#pragma unroll
    for (int i = 0; i < 4; ++i) {
      const float4 av = pa[4 * c4 + i];
      const float4 bv = pb[4 * c4 + i];
      const float x0 = fmaxf(av.x + bv.x, 0.f);
      const float x1 = fmaxf(av.y + bv.y, 0.f);
      const float x2 = fmaxf(av.z + bv.z, 0.f);
      const float x3 = fmaxf(av.w + bv.w, 0.f);
      xch[4 * i + 0] = x0; xch[4 * i + 1] = x1;
      xch[4 * i + 2] = x2; xch[4 * i + 3] = x3;
      s += x0; s += x1; s += x2; s += x3;
      q = fmaf(x0, x0, q); q = fmaf(x1, x1, q);
      q = fmaf(x2, x2, q); q = fmaf(x3, x3, q);
    }
#pragma unroll
    for (int kk = 0; kk < 16; ++kk) {
      const int k = 16 * c4 + kk;
      cfloat* wk = W + k * FF;
      const float xs = xch[kk];
      f32x2 xb; xb.x = xs; xb.y = xs;
#pragma unroll
      for (int jp = 0; jp < 32; ++jp) {
        f32x2 wp; wp.x = wk[2 * jp]; wp.y = wk[2 * jp + 1];  // uniform -> s_load
        t2[jp] = PKFMA(xb, wp, t2[jp]);
      }
    }
  }

  // ---- epilogue: fully per-lane ----
  const float mu = s * (1.f / FF);
  const float rstd = 1.f / sqrtf(q * (1.f / FF) - mu * mu + 1e-5f);

  float s1 = 0.f, s2 = 0.f, s3 = 0.f;
#pragma unroll
  for (int j = 0; j < FF; ++j) {
    const float tv = (j & 1) ? t2[j >> 1].y : t2[j >> 1].x;
    const float pre = fmaf(rstd, fmaf(-mu, wcol[j], tv), cbc[j]);
    const float tr = fmaxf(pre, 0.f);
    s1 += tr;
    s2 = fmaf(tr, tr, s2);
    s3 = fmaf(tr, gwc[j], s3);
  }
  const float cw = cwsgw[0], sgw = cwsgw[1];
  const float mu2 = s1 * (1.f / FF);
  const float var2 = s2 * (1.f / FF) - mu2 * mu2;
  const float rstd2 = 1.f / sqrtf(var2 + 1e-5f);
  const float logit = fmaf(rstd2, fmaf(-mu2, sgw, s3), cw);
  L[(b * NSINK + (r - TT)) * NSRC + c] = logit;
}

// ---------------- argmax over sources + scatter ones ----------------
__global__ __launch_bounds__(256) void argmax_scatter(
    const float* __restrict__ L, const float* __restrict__ gum,
    float* __restrict__ out) {
  const int task = blockIdx.x * 4 + (threadIdx.x >> 6);  // ((s*B+b)*192+row)
  const int lane = threadIdx.x & 63;
  const int row = task % NSINK;
  const int sb = task / NSINK;   // s*B + b
  const int b = sb & 7;
  const int r = row + TT;

  const float* __restrict__ lrow = L + (b * NSINK + row) * NSRC;
  const float* __restrict__ grow = gum + task * NSRC;

  float bv = -INFINITY;
  int bi = 0;
  for (int c = lane; c < r; c += 64) {
    const float v = lrow[c] + grow[c];
    if (v > bv) { bv = v; bi = c; }   // strict > keeps smallest index per lane
  }
#pragma unroll
  for (int off = 32; off > 0; off >>= 1) {
    const float ov = __shfl_xor(bv, off, 64);
    const int oi = __shfl_xor(bi, off, 64);
    if (ov > bv || (ov == bv && oi < bi)) { bv = ov; bi = oi; }
  }
  if (lane == 0) out[(b * NN + r) * NN + bi] = 1.0f;
}

extern "C" void kernel_launch(void* const* d_in, const int* in_sizes, int n_in,
                              void* d_out, int out_size, void* d_ws, size_t ws_size,
                              hipStream_t stream) {
  const float* nodes = (const float*)d_in[0];
  const float* w1 = (const float*)d_in[1];
  const float* b1 = (const float*)d_in[2];
  const float* g1 = (const float*)d_in[3];
  const float* be1 = (const float*)d_in[4];
  const float* w2 = (const float*)d_in[5];
  const float* b2 = (const float*)d_in[6];
  const float* g2 = (const float*)d_in[7];
  const float* be2 = (const float*)d_in[8];
  const float* w3 = (const float*)d_in[9];
  const float* b3 = (const float*)d_in[10];
  const float* gum = (const float*)d_in[11];
  const int* bidx = (const int*)d_in[12];
  const int* ridx = (const int*)d_in[13];
  const int* cidx = (const int*)d_in[14];
  float* out = (float*)d_out;

  // workspace layout (floats)
  float* ws = (float*)d_ws;
  float* A = ws;                       // 8*384*64 = 196608
  float* Bv = A + BN * FF;             // 196608
  float* W2kj = Bv + BN * FF;          // 4096
  float* wcol = W2kj + FF * FF;        // 64
  float* cb = wcol + FF;               // 64
  float* gw = cb + FF;                 // 64
  float* cwsgw = gw + FF;              // 2
  float* L = ws + 397520;              // 8*192*383 = 588288
  (void)ws_size; (void)n_in; (void)in_sizes; (void)out_size;

  hipLaunchKernelGGL(prep_all, dim3(BN / 4 + 1), dim3(64), 0, stream,
                     nodes, w1, b1, w2, b2, g1, be1, g2, be2, w3, b3,
                     A, Bv, W2kj, wcol, cb, gw, cwsgw);
  hipLaunchKernelGGL(edge_mlp, dim3(NBLKE), dim3(256), 0, stream,
                     A, Bv, W2kj, wcol, cb, gw, cwsgw, bidx, ridx, cidx, L,
                     (float4*)out);
  hipLaunchKernelGGL(argmax_scatter, dim3((SS * BB * NSINK) / 4), dim3(256), 0, stream,
                     L, gum, out);
}

// Round 12
// 156.802 us; speedup vs baseline: 1.0664x; 1.0354x over previous
//
#include <hip/hip_runtime.h>
#include <math.h>
#include <stdint.h>

// Problem constants (static per reference)
#define BB 8
#define NN 384
#define FF 64
#define TT 192
#define NSRC 383          // T + TAU - 1
#define NSINK 192
#define SS 5
#define NEDGE 441600      // B * 55200
#define BN (BB * NN)      // 3072
#define TILE_E 256        // edges per block (4 waves x 64, lane <-> edge)
#define NBLKE (NEDGE / TILE_E)    // 1725 exactly
#define OUTV ((BB * NN * NN) / 4) // 294912 float4 to zero

typedef float f32x2 __attribute__((ext_vector_type(2)));

#if defined(__has_builtin) && __has_builtin(__builtin_elementwise_fma)
#define PKFMA(a, b, c) __builtin_elementwise_fma((a), (b), (c))
#else
#define PKFMA(a, b, c) ((a) * (b) + (c))
#endif

// ---------------- prep: node projections (4 rows/block) + weight folding ----------------
__global__ __launch_bounds__(64) void prep_all(
    const float* __restrict__ nodes, const float* __restrict__ w1,
    const float* __restrict__ b1,
    const float* __restrict__ w2, const float* __restrict__ b2,
    const float* __restrict__ g1, const float* __restrict__ be1,
    const float* __restrict__ g2, const float* __restrict__ be2,
    const float* __restrict__ w3, const float* __restrict__ b3,
    float* __restrict__ A, float* __restrict__ Bv,
    float* __restrict__ W2kj, float* __restrict__ wcol,
    float* __restrict__ cb, float* __restrict__ gw,
    float* __restrict__ cwsgw) {
  const int blk = blockIdx.x;
  const int k = threadIdx.x;
  if (blk < BN / 4) {
    const int bn0 = blk * 4;
    __shared__ float nd[4][FF];
#pragma unroll
    for (int i = 0; i < 4; ++i) nd[i][k] = nodes[(bn0 + i) * FF + k];
    __syncthreads();
    const float bk = b1[k];
    float a0 = bk, a1 = bk, a2 = bk, a3 = bk;
    float q0 = 0.f, q1 = 0.f, q2 = 0.f, q3 = 0.f;
#pragma unroll 8
    for (int f = 0; f < FF; ++f) {
      const float wt = w1[f * FF + k];
      const float wb = w1[(FF + f) * FF + k];
      const float n0 = nd[0][f], n1 = nd[1][f], n2 = nd[2][f], n3 = nd[3][f];
      a0 = fmaf(n0, wt, a0); a1 = fmaf(n1, wt, a1);
      a2 = fmaf(n2, wt, a2); a3 = fmaf(n3, wt, a3);
      q0 = fmaf(n0, wb, q0); q1 = fmaf(n1, wb, q1);
      q2 = fmaf(n2, wb, q2); q3 = fmaf(n3, wb, q3);
    }
    A[(bn0 + 0) * FF + k] = a0;  Bv[(bn0 + 0) * FF + k] = q0;
    A[(bn0 + 1) * FF + k] = a1;  Bv[(bn0 + 1) * FF + k] = q1;
    A[(bn0 + 2) * FF + k] = a2;  Bv[(bn0 + 2) * FF + k] = q2;
    A[(bn0 + 3) * FF + k] = a3;  Bv[(bn0 + 3) * FF + k] = q3;
  } else {
    const int j = k;
    float cbj = b2[j];
    float wc = 0.f;
    for (int kk = 0; kk < FF; ++kk) {
      const float wraw = w2[kk * FF + j];
      const float w = g1[kk] * wraw;
      W2kj[kk * FF + j] = w;
      wc += w;
      cbj = fmaf(be1[kk], wraw, cbj);
    }
    wcol[j] = wc;
    cb[j] = cbj;
    const float gwj = g2[j] * w3[j];
    gw[j] = gwj;
    __shared__ float sA[FF], sB[FF];
    sA[j] = gwj;
    sB[j] = be2[j] * w3[j];
    __syncthreads();
    if (j == 0) {
      float a = 0.f, bq = 0.f;
      for (int i = 0; i < FF; ++i) { a += sA[i]; bq += sB[i]; }
      cwsgw[0] = b3[0] + bq;
      cwsgw[1] = a;
    }
  }
}

// ---------------- main: r9 topology, scratch-free epilogue ----------------
// 256 thr = 4 waves; wave owns 64 edges, lane <-> edge in phase 1.
// phase 2: lane (eg3=lane>>3, joct=lane&7) -> 8 edges x 8 j, 32 f32x2 accums.
// epilogue: partials -> wave-private LDS (reusing the dead X slab), no reg arrays.
__global__ __launch_bounds__(256, 2) void edge_mlp(
    const float* __restrict__ A, const float* __restrict__ Bv,
    const float* __restrict__ W2kj, const float* __restrict__ wcolg,
    const float* __restrict__ cbg, const float* __restrict__ gwg,
    const float* __restrict__ cwsgw,
    const int* __restrict__ bidx, const int* __restrict__ ridx,
    const int* __restrict__ cidx, float* __restrict__ L,
    float4* __restrict__ outv) {
  __shared__ float Wl[FF][FF];       // 16 KB, k-major
  __shared__ float X[4][FF][64];     // 64 KB: [wave][k][edge]

  const int tid = threadIdx.x;       // 0..255
  const int wave = tid >> 6;
  const int lane = tid & 63;

  // fused zeroing of the output grid (1725*256 = 441600 >= OUTV)
  const int gtid = blockIdx.x * 256 + tid;
  if (gtid < OUTV) outv[gtid] = make_float4(0.f, 0.f, 0.f, 0.f);

  // ---- stage W2 (4096 floats = 1024 float4, 4/thread, coalesced) ----
  {
    const float4* src = (const float4*)W2kj;
    float4* dst = (float4*)&Wl[0][0];
#pragma unroll
    for (int i = 0; i < 4; ++i) dst[tid + 256 * i] = src[tid + 256 * i];
  }

  // ---- phase 1: lane <-> edge; gather all 64 k, relu, stats in-register ----
  const int ge = blockIdx.x * TILE_E + tid;
  const int b = bidx[ge], r = ridx[ge], c = cidx[ge];
  float mu, rstd;
  {
    const float4* pa = (const float4*)(A + (b * NN + r) * FF);
    const float4* pb = (const float4*)(Bv + (b * NN + c) * FF);
    float s = 0.f, q = 0.f;
#pragma unroll
    for (int i = 0; i < 16; ++i) {
      const float4 av = pa[i];
      const float4 bv = pb[i];
      const float x0 = fmaxf(av.x + bv.x, 0.f);
      const float x1 = fmaxf(av.y + bv.y, 0.f);
      const float x2 = fmaxf(av.z + bv.z, 0.f);
      const float x3 = fmaxf(av.w + bv.w, 0.f);
      const int kb = 4 * i;
      X[wave][kb + 0][lane] = x0;
      X[wave][kb + 1][lane] = x1;
      X[wave][kb + 2][lane] = x2;
      X[wave][kb + 3][lane] = x3;
      s += x0; s += x1; s += x2; s += x3;
      q = fmaf(x0, x0, q); q = fmaf(x1, x1, q);
      q = fmaf(x2, x2, q); q = fmaf(x3, x3, q);
    }
    mu = s * (1.f / FF);
    rstd = 1.f / sqrtf(q * (1.f / FF) - mu * mu + 1e-5f);
  }

  __syncthreads();   // W staging + X slabs visible block-wide

  // ---- phase 2: k-loop, 8 edges x 8 j per lane, packed f32x2 ----
  const int joct = lane & 7;
  const int eg3 = lane >> 3;
  f32x2 t2[8][4];
#pragma unroll
  for (int ei = 0; ei < 8; ++ei)
#pragma unroll
    for (int p = 0; p < 4; ++p) t2[ei][p] = (f32x2){0.f, 0.f};

  const float* xrow = &X[wave][0][8 * eg3];   // +64 floats per k
  const float* wrow = &Wl[0][8 * joct];       // +64 floats per k
#pragma unroll 4
  for (int k = 0; k < FF; ++k) {
    const float4 xA = *(const float4*)xrow;
    const float4 xB = *(const float4*)(xrow + 4);
    xrow += 64;
    const float4 wA = *(const float4*)wrow;
    const float4 wB = *(const float4*)(wrow + 4);
    wrow += 64;
    f32x2 w01; w01.x = wA.x; w01.y = wA.y;
    f32x2 w23; w23.x = wA.z; w23.y = wA.w;
    f32x2 w45; w45.x = wB.x; w45.y = wB.y;
    f32x2 w67; w67.x = wB.z; w67.y = wB.w;
    const float xe[8] = {xA.x, xA.y, xA.z, xA.w, xB.x, xB.y, xB.z, xB.w};
#pragma unroll
    for (int ei = 0; ei < 8; ++ei) {
      f32x2 xb; xb.x = xe[ei]; xb.y = xe[ei];
      t2[ei][0] = PKFMA(xb, w01, t2[ei][0]);
      t2[ei][1] = PKFMA(xb, w23, t2[ei][1]);
      t2[ei][2] = PKFMA(xb, w45, t2[ei][2]);
      t2[ei][3] = PKFMA(xb, w67, t2[ei][3]);
    }
  }

  // ---- epilogue: per-ei scalar partials -> wave-private LDS (X slab reuse) ----
  const float4 wc4a = *(const float4*)(wcolg + 8 * joct);
  const float4 wc4b = *(const float4*)(wcolg + 8 * joct + 4);
  const float4 cb4a = *(const float4*)(cbg + 8 * joct);
  const float4 cb4b = *(const float4*)(cbg + 8 * joct + 4);
  const float4 gw4a = *(const float4*)(gwg + 8 * joct);
  const float4 gw4b = *(const float4*)(gwg + 8 * joct + 4);

  // X[wave] is dead for this wave's k-loop now (each wave reads only its slab).
  float* Sp = &X[wave][0][0];   // rows of 33 dwords: edge e at Sp[33*e + 4*joct]
  const int base8 = lane & 56;  // 8*eg3

  __builtin_amdgcn_wave_barrier();  // keep compiler from sinking X reads past writes

#pragma unroll
  for (int ei = 0; ei < 8; ++ei) {
    const float m = __shfl(mu, base8 + ei, 64);
    const float rs = __shfl(rstd, base8 + ei, 64);
    float a1 = 0.f, a2 = 0.f, a3 = 0.f;
    {
      float tv, pre, tr;
      tv = t2[ei][0].x;
      pre = fmaf(rs, fmaf(-m, wc4a.x, tv), cb4a.x); tr = fmaxf(pre, 0.f);
      a1 += tr; a2 = fmaf(tr, tr, a2); a3 = fmaf(tr, gw4a.x, a3);
      tv = t2[ei][0].y;
      pre = fmaf(rs, fmaf(-m, wc4a.y, tv), cb4a.y); tr = fmaxf(pre, 0.f);
      a1 += tr; a2 = fmaf(tr, tr, a2); a3 = fmaf(tr, gw4a.y, a3);
      tv = t2[ei][1].x;
      pre = fmaf(rs, fmaf(-m, wc4a.z, tv), cb4a.z); tr = fmaxf(pre, 0.f);
      a1 += tr; a2 = fmaf(tr, tr, a2); a3 = fmaf(tr, gw4a.z, a3);
      tv = t2[ei][1].y;
      pre = fmaf(rs, fmaf(-m, wc4a.w, tv), cb4a.w); tr = fmaxf(pre, 0.f);
      a1 += tr; a2 = fmaf(tr, tr, a2); a3 = fmaf(tr, gw4a.w, a3);
      tv = t2[ei][2].x;
      pre = fmaf(rs, fmaf(-m, wc4b.x, tv), cb4b.x); tr = fmaxf(pre, 0.f);
      a1 += tr; a2 = fmaf(tr, tr, a2); a3 = fmaf(tr, gw4b.x, a3);
      tv = t2[ei][2].y;
      pre = fmaf(rs, fmaf(-m, wc4b.y, tv), cb4b.y); tr = fmaxf(pre, 0.f);
      a1 += tr; a2 = fmaf(tr, tr, a2); a3 = fmaf(tr, gw4b.y, a3);
      tv = t2[ei][3].x;
      pre = fmaf(rs, fmaf(-m, wc4b.z, tv), cb4b.z); tr = fmaxf(pre, 0.f);
      a1 += tr; a2 = fmaf(tr, tr, a2); a3 = fmaf(tr, gw4b.z, a3);
      tv = t2[ei][3].y;
      pre = fmaf(rs, fmaf(-m, wc4b.w, tv), cb4b.w); tr = fmaxf(pre, 0.f);
      a1 += tr; a2 = fmaf(tr, tr, a2); a3 = fmaf(tr, gw4b.w, a3);
    }
    // edge (8*eg3 + ei), slot joct; 33-dword row stride -> 2-way banks (free)
    float4* slot = (float4*)(Sp + 33 * (base8 + ei) + 4 * joct);
    *slot = make_float4(a1, a2, a3, 0.f);
  }

  __builtin_amdgcn_wave_barrier();  // wave-local RAW; DS pipe is in-order per wave

  // ---- finalize: lane merges the 8 j-octet partials of ITS OWN edge ----
  {
    const float* row = Sp + 33 * lane;
    float S1 = 0.f, S2 = 0.f, S3 = 0.f;
#pragma unroll
    for (int jo = 0; jo < 8; ++jo) {
      const float4 p4 = *(const float4*)(row + 4 * jo);
      S1 += p4.x; S2 += p4.y; S3 += p4.z;
    }
    const float cw = cwsgw[0], sgw = cwsgw[1];
    const float mu2 = S1 * (1.f / FF);
    const float var2 = S2 * (1.f / FF) - mu2 * mu2;
    const float rstd2 = 1.f / sqrtf(var2 + 1e-5f);
    const float logit = fmaf(rstd2, fmaf(-mu2, sgw, S3), cw);
    L[(b * NSINK + (r - TT)) * NSRC + c] = logit;
  }
}

// ---------------- argmax over sources + scatter ones ----------------
__global__ __launch_bounds__(256) void argmax_scatter(
    const float* __restrict__ L, const float* __restrict__ gum,
    float* __restrict__ out) {
  const int task = blockIdx.x * 4 + (threadIdx.x >> 6);  // ((s*B+b)*192+row)
  const int lane = threadIdx.x & 63;
  const int row = task % NSINK;
  const int sb = task / NSINK;   // s*B + b
  const int b = sb & 7;
  const int r = row + TT;

  const float* __restrict__ lrow = L + (b * NSINK + row) * NSRC;
  const float* __restrict__ grow = gum + task * NSRC;

  float bv = -INFINITY;
  int bi = 0;
  for (int c = lane; c < r; c += 64) {
    const float v = lrow[c] + grow[c];
    if (v > bv) { bv = v; bi = c; }   // strict > keeps smallest index per lane
  }
#pragma unroll
  for (int off = 32; off > 0; off >>= 1) {
    const float ov = __shfl_xor(bv, off, 64);
    const int oi = __shfl_xor(bi, off, 64);
    if (ov > bv || (ov == bv && oi < bi)) { bv = ov; bi = oi; }
  }
  if (lane == 0) out[(b * NN + r) * NN + bi] = 1.0f;
}

extern "C" void kernel_launch(void* const* d_in, const int* in_sizes, int n_in,
                              void* d_out, int out_size, void* d_ws, size_t ws_size,
                              hipStream_t stream) {
  const float* nodes = (const float*)d_in[0];
  const float* w1 = (const float*)d_in[1];
  const float* b1 = (const float*)d_in[2];
  const float* g1 = (const float*)d_in[3];
  const float* be1 = (const float*)d_in[4];
  const float* w2 = (const float*)d_in[5];
  const float* b2 = (const float*)d_in[6];
  const float* g2 = (const float*)d_in[7];
  const float* be2 = (const float*)d_in[8];
  const float* w3 = (const float*)d_in[9];
  const float* b3 = (const float*)d_in[10];
  const float* gum = (const float*)d_in[11];
  const int* bidx = (const int*)d_in[12];
  const int* ridx = (const int*)d_in[13];
  const int* cidx = (const int*)d_in[14];
  float* out = (float*)d_out;

  // workspace layout (floats)
  float* ws = (float*)d_ws;
  float* A = ws;                       // 8*384*64 = 196608
  float* Bv = A + BN * FF;             // 196608
  float* W2kj = Bv + BN * FF;          // 4096
  float* wcol = W2kj + FF * FF;        // 64
  float* cb = wcol + FF;               // 64
  float* gw = cb + FF;                 // 64
  float* cwsgw = gw + FF;              // 2
  float* L = ws + 397520;              // 8*192*383 = 588288
  (void)ws_size; (void)n_in; (void)in_sizes; (void)out_size;

  hipLaunchKernelGGL(prep_all, dim3(BN / 4 + 1), dim3(64), 0, stream,
                     nodes, w1, b1, w2, b2, g1, be1, g2, be2, w3, b3,
                     A, Bv, W2kj, wcol, cb, gw, cwsgw);
  hipLaunchKernelGGL(edge_mlp, dim3(NBLKE), dim3(256), 0, stream,
                     A, Bv, W2kj, wcol, cb, gw, cwsgw, bidx, ridx, cidx, L,
                     (float4*)out);
  hipLaunchKernelGGL(argmax_scatter, dim3((SS * BB * NSINK) / 4), dim3(256), 0, stream,
                     L, gum, out);
}

// Round 13
// 138.857 us; speedup vs baseline: 1.2042x; 1.1292x over previous
//
#include <hip/hip_runtime.h>
#include <math.h>
#include <stdint.h>

// Problem constants (static per reference)
#define BB 8
#define NN 384
#define FF 64
#define TT 192
#define NSRC 383          // T + TAU - 1
#define NSINK 192
#define SS 5
#define NEDGE 441600      // B * 55200
#define BN (BB * NN)      // 3072
#define TILE_E 256        // edges per block (4 waves x 64, lane <-> edge)
#define NBLKE (NEDGE / TILE_E)    // 1725 exactly
#define OUTV ((BB * NN * NN) / 4) // 294912 float4 to zero

typedef _Float16 half8 __attribute__((ext_vector_type(8)));
typedef float floatx4 __attribute__((ext_vector_type(4)));

// 2-limb f16 split: x ~= h + l/512 (l scaled to avoid f16 subnormals)
static __device__ __forceinline__ void split_f16(float x, uint16_t& h, uint16_t& l) {
  const _Float16 hh = (_Float16)x;          // RNE
  const float hb = (float)hh;
  const _Float16 ll = (_Float16)((x - hb) * 512.f);
  h = __builtin_bit_cast(uint16_t, hh);
  l = __builtin_bit_cast(uint16_t, ll);
}

// ---------------- prep: node projections + weight folding + W f16-limb frags ----------------
// W frag slab (A-operand layout, per limb): ushort idx = (((jt*2+kc)*4+q)*16 + m)*8 + jj
//   <-> W[k = 32*kc + 8*q + jj][j = 16*jt + m]   (g1-folded weight)
__global__ __launch_bounds__(64) void prep_all(
    const float* __restrict__ nodes, const float* __restrict__ w1,
    const float* __restrict__ b1,
    const float* __restrict__ w2, const float* __restrict__ b2,
    const float* __restrict__ g1, const float* __restrict__ be1,
    const float* __restrict__ g2, const float* __restrict__ be2,
    const float* __restrict__ w3, const float* __restrict__ b3,
    float* __restrict__ A, float* __restrict__ Bv,
    unsigned short* __restrict__ Whg, unsigned short* __restrict__ Wlg,
    float* __restrict__ wcol, float* __restrict__ cb,
    float* __restrict__ gw, float* __restrict__ cwsgw) {
  const int blk = blockIdx.x;
  const int k = threadIdx.x;
  if (blk < BN / 4) {
    const int bn0 = blk * 4;
    __shared__ float nd[4][FF];
#pragma unroll
    for (int i = 0; i < 4; ++i) nd[i][k] = nodes[(bn0 + i) * FF + k];
    __syncthreads();
    const float bk = b1[k];
    float a0 = bk, a1 = bk, a2 = bk, a3 = bk;
    float q0 = 0.f, q1 = 0.f, q2 = 0.f, q3 = 0.f;
#pragma unroll 8
    for (int f = 0; f < FF; ++f) {
      const float wt = w1[f * FF + k];
      const float wb = w1[(FF + f) * FF + k];
      const float n0 = nd[0][f], n1 = nd[1][f], n2 = nd[2][f], n3 = nd[3][f];
      a0 = fmaf(n0, wt, a0); a1 = fmaf(n1, wt, a1);
      a2 = fmaf(n2, wt, a2); a3 = fmaf(n3, wt, a3);
      q0 = fmaf(n0, wb, q0); q1 = fmaf(n1, wb, q1);
      q2 = fmaf(n2, wb, q2); q3 = fmaf(n3, wb, q3);
    }
    A[(bn0 + 0) * FF + k] = a0;  Bv[(bn0 + 0) * FF + k] = q0;
    A[(bn0 + 1) * FF + k] = a1;  Bv[(bn0 + 1) * FF + k] = q1;
    A[(bn0 + 2) * FF + k] = a2;  Bv[(bn0 + 2) * FF + k] = q2;
    A[(bn0 + 3) * FF + k] = a3;  Bv[(bn0 + 3) * FF + k] = q3;
  } else {
    const int j = k;
    const int jt = j >> 4, m = j & 15;
    float cbj = b2[j];
    float wc = 0.f;
    for (int kk = 0; kk < FF; ++kk) {
      const float wraw = w2[kk * FF + j];
      const float w = g1[kk] * wraw;
      wc += w;
      cbj = fmaf(be1[kk], wraw, cbj);
      uint16_t hu, lu;
      split_f16(w, hu, lu);
      const int kc = kk >> 5, qq = (kk >> 3) & 3, jj = kk & 7;
      const int idx = (((jt * 2 + kc) * 4 + qq) * 16 + m) * 8 + jj;
      Whg[idx] = hu;
      Wlg[idx] = lu;
    }
    wcol[j] = wc;
    cb[j] = cbj;
    const float gwj = g2[j] * w3[j];
    gw[j] = gwj;
    __shared__ float sA[FF], sB[FF];
    sA[j] = gwj;
    sB[j] = be2[j] * w3[j];
    __syncthreads();
    if (j == 0) {
      float a = 0.f, bq = 0.f;
      for (int i = 0; i < FF; ++i) { a += sA[i]; bq += sB[i]; }
      cwsgw[0] = b3[0] + bq;
      cwsgw[1] = a;
    }
  }
}

// ---------------- main: MFMA edge MLP. D = W^T(64j x 64k) * X(64k x 64e) per wave ----------------
// 256 thr = 4 waves, wave owns 64 edges (local edge = lane).
// mfma_f32_16x16x32_f16 layouts: A[m=lane&15][k=8*(lane>>4)+jj]; D col=lane&15, row=4*(lane>>4)+reg.
__global__ __launch_bounds__(256, 2) void edge_mlp(
    const float* __restrict__ A, const float* __restrict__ Bv,
    const unsigned short* __restrict__ Whg, const unsigned short* __restrict__ Wlg,
    const float* __restrict__ wcolg, const float* __restrict__ cbg,
    const float* __restrict__ gwg, const float* __restrict__ cwsgw,
    const int* __restrict__ bidx, const int* __restrict__ ridx,
    const int* __restrict__ cidx, float* __restrict__ L,
    float4* __restrict__ outv) {
  __shared__ __align__(16) unsigned short WHs[4096];    //  8 KB  W hi frags
  __shared__ __align__(16) unsigned short WLs[4096];    //  8 KB  W lo frags
  __shared__ __align__(16) unsigned short XHs[16384];   // 32 KB  X hi frags (4 waves)
  __shared__ __align__(16) unsigned short XLs[16384];   // 32 KB  X lo frags

  const int tid = threadIdx.x;       // 0..255
  const int wave = tid >> 6;
  const int lane = tid & 63;

  // fused zeroing of the output grid
  const int gtid = blockIdx.x * 256 + tid;
  if (gtid < OUTV) outv[gtid] = make_float4(0.f, 0.f, 0.f, 0.f);

  // ---- stage W frag slabs (coalesced int4) ----
  {
    const int4* sh = (const int4*)Whg;
    const int4* sl = (const int4*)Wlg;
    int4* dh = (int4*)WHs;
    int4* dl = (int4*)WLs;
    dh[tid] = sh[tid]; dh[tid + 256] = sh[tid + 256];
    dl[tid] = sl[tid]; dl[tid + 256] = sl[tid + 256];
  }

  // ---- phase 1: lane <-> edge; gather, relu, stats, f16-split into B-frag layout ----
  const int ge = blockIdx.x * TILE_E + tid;
  const int b = bidx[ge], r = ridx[ge], c = cidx[ge];
  const int et_own = lane >> 4, n_own = lane & 15;
  float mu, rstd;
  {
    const float4* pa = (const float4*)(A + (b * NN + r) * FF);
    const float4* pb = (const float4*)(Bv + (b * NN + c) * FF);
    unsigned short* dh = &XHs[wave * 4096 + n_own * 8];
    unsigned short* dl = &XLs[wave * 4096 + n_own * 8];
    float s = 0.f, q = 0.f;
#pragma unroll
    for (int g = 0; g < 8; ++g) {     // g -> k in [8g, 8g+8): kc=g>>2, q=g&3
      const float4 av0 = pa[2 * g], av1 = pa[2 * g + 1];
      const float4 bv0 = pb[2 * g], bv1 = pb[2 * g + 1];
      const float x0 = fmaxf(av0.x + bv0.x, 0.f);
      const float x1 = fmaxf(av0.y + bv0.y, 0.f);
      const float x2 = fmaxf(av0.z + bv0.z, 0.f);
      const float x3 = fmaxf(av0.w + bv0.w, 0.f);
      const float x4 = fmaxf(av1.x + bv1.x, 0.f);
      const float x5 = fmaxf(av1.y + bv1.y, 0.f);
      const float x6 = fmaxf(av1.z + bv1.z, 0.f);
      const float x7 = fmaxf(av1.w + bv1.w, 0.f);
      s += x0 + x1 + x2 + x3 + x4 + x5 + x6 + x7;
      q = fmaf(x0, x0, q); q = fmaf(x1, x1, q);
      q = fmaf(x2, x2, q); q = fmaf(x3, x3, q);
      q = fmaf(x4, x4, q); q = fmaf(x5, x5, q);
      q = fmaf(x6, x6, q); q = fmaf(x7, x7, q);
      uint16_t h0, h1, h2, h3, h4, h5, h6, h7;
      uint16_t l0, l1, l2, l3, l4, l5, l6, l7;
      split_f16(x0, h0, l0); split_f16(x1, h1, l1);
      split_f16(x2, h2, l2); split_f16(x3, h3, l3);
      split_f16(x4, h4, l4); split_f16(x5, h5, l5);
      split_f16(x6, h6, l6); split_f16(x7, h7, l7);
      const int choff = ((et_own * 2 + (g >> 2)) * 4 + (g & 3)) * 128;
      int4 hi4, lo4;
      hi4.x = (int)((uint32_t)h0 | ((uint32_t)h1 << 16));
      hi4.y = (int)((uint32_t)h2 | ((uint32_t)h3 << 16));
      hi4.z = (int)((uint32_t)h4 | ((uint32_t)h5 << 16));
      hi4.w = (int)((uint32_t)h6 | ((uint32_t)h7 << 16));
      lo4.x = (int)((uint32_t)l0 | ((uint32_t)l1 << 16));
      lo4.y = (int)((uint32_t)l2 | ((uint32_t)l3 << 16));
      lo4.z = (int)((uint32_t)l4 | ((uint32_t)l5 << 16));
      lo4.w = (int)((uint32_t)l6 | ((uint32_t)l7 << 16));
      *(int4*)(dh + choff) = hi4;
      *(int4*)(dl + choff) = lo4;
    }
    mu = s * (1.f / FF);
    rstd = 1.f / sqrtf(q * (1.f / FF) - mu * mu + 1e-5f);
  }

  __syncthreads();   // W slabs + all X slabs visible

  // ---- phase 2: MFMA K-loops + per-et epilogue ----
  const int q4 = lane >> 4;      // quad
  const int c15 = lane & 15;

  // per-lane j-constants: j = 16*jt + 4*q4 + reg
  floatx4 wc4[4], cb4[4], gw4[4];
#pragma unroll
  for (int jt = 0; jt < 4; ++jt) {
    wc4[jt] = *(const floatx4*)(wcolg + 16 * jt + 4 * q4);
    cb4[jt] = *(const floatx4*)(cbg + 16 * jt + 4 * q4);
    gw4[jt] = *(const floatx4*)(gwg + 16 * jt + 4 * q4);
  }
  const float cw = cwsgw[0], sgw = cwsgw[1];

#pragma unroll
  for (int et = 0; et < 4; ++et) {
    floatx4 acc0[4], acc1[4];
#pragma unroll
    for (int jt = 0; jt < 4; ++jt) {
      acc0[jt] = (floatx4){0.f, 0.f, 0.f, 0.f};
      acc1[jt] = (floatx4){0.f, 0.f, 0.f, 0.f};
    }
#pragma unroll
    for (int kc = 0; kc < 2; ++kc) {
      const int xoff = wave * 4096 + ((et * 2 + kc) * 4 + q4) * 128 + c15 * 8;
      const half8 xh = *(const half8*)&XHs[xoff];
      const half8 xl = *(const half8*)&XLs[xoff];
#pragma unroll
      for (int jt = 0; jt < 4; ++jt) {
        const int woff = ((jt * 2 + kc) * 4 + q4) * 128 + c15 * 8;
        const half8 wh = *(const half8*)&WHs[woff];
        const half8 wl = *(const half8*)&WLs[woff];
        acc0[jt] = __builtin_amdgcn_mfma_f32_16x16x32_f16(wh, xh, acc0[jt], 0, 0, 0);
        acc1[jt] = __builtin_amdgcn_mfma_f32_16x16x32_f16(wh, xl, acc1[jt], 0, 0, 0);
        acc1[jt] = __builtin_amdgcn_mfma_f32_16x16x32_f16(wl, xh, acc1[jt], 0, 0, 0);
      }
    }
    // ---- epilogue for edges e = 16*et + c15 ----
    const int e2 = 16 * et + c15;
    const float mue = __shfl(mu, e2, 64);
    const float rse = __shfl(rstd, e2, 64);
    float s1 = 0.f, s2 = 0.f, s3 = 0.f;
#pragma unroll
    for (int jt = 0; jt < 4; ++jt) {
      const floatx4 t4 = acc0[jt] + acc1[jt] * (1.f / 512.f);
#pragma unroll
      for (int rg = 0; rg < 4; ++rg) {
        const float pre = fmaf(rse, fmaf(-mue, wc4[jt][rg], t4[rg]), cb4[jt][rg]);
        const float tr = fmaxf(pre, 0.f);
        s1 += tr;
        s2 = fmaf(tr, tr, s2);
        s3 = fmaf(tr, gw4[jt][rg], s3);
      }
    }
    // sum over the 4 quads (each quad covered a disjoint 16-j subset)
    s1 += __shfl_xor(s1, 16, 64); s1 += __shfl_xor(s1, 32, 64);
    s2 += __shfl_xor(s2, 16, 64); s2 += __shfl_xor(s2, 32, 64);
    s3 += __shfl_xor(s3, 16, 64); s3 += __shfl_xor(s3, 32, 64);
    if (q4 == 0) {
      const int ge2 = blockIdx.x * TILE_E + wave * 64 + e2;
      const int b2 = bidx[ge2], r2 = ridx[ge2], c2 = cidx[ge2];
      const float mu2 = s1 * (1.f / FF);
      const float var2 = s2 * (1.f / FF) - mu2 * mu2;
      const float rstd2 = 1.f / sqrtf(var2 + 1e-5f);
      const float logit = fmaf(rstd2, fmaf(-mu2, sgw, s3), cw);
      L[(b2 * NSINK + (r2 - TT)) * NSRC + c2] = logit;
    }
  }
}

// ---------------- argmax over sources + scatter ones ----------------
__global__ __launch_bounds__(256) void argmax_scatter(
    const float* __restrict__ L, const float* __restrict__ gum,
    float* __restrict__ out) {
  const int task = blockIdx.x * 4 + (threadIdx.x >> 6);  // ((s*B+b)*192+row)
  const int lane = threadIdx.x & 63;
  const int row = task % NSINK;
  const int sb = task / NSINK;   // s*B + b
  const int b = sb & 7;
  const int r = row + TT;

  const float* __restrict__ lrow = L + (b * NSINK + row) * NSRC;
  const float* __restrict__ grow = gum + task * NSRC;

  float bv = -INFINITY;
  int bi = 0;
  for (int c = lane; c < r; c += 64) {
    const float v = lrow[c] + grow[c];
    if (v > bv) { bv = v; bi = c; }   // strict > keeps smallest index per lane
  }
#pragma unroll
  for (int off = 32; off > 0; off >>= 1) {
    const float ov = __shfl_xor(bv, off, 64);
    const int oi = __shfl_xor(bi, off, 64);
    if (ov > bv || (ov == bv && oi < bi)) { bv = ov; bi = oi; }
  }
  if (lane == 0) out[(b * NN + r) * NN + bi] = 1.0f;
}

extern "C" void kernel_launch(void* const* d_in, const int* in_sizes, int n_in,
                              void* d_out, int out_size, void* d_ws, size_t ws_size,
                              hipStream_t stream) {
  const float* nodes = (const float*)d_in[0];
  const float* w1 = (const float*)d_in[1];
  const float* b1 = (const float*)d_in[2];
  const float* g1 = (const float*)d_in[3];
  const float* be1 = (const float*)d_in[4];
  const float* w2 = (const float*)d_in[5];
  const float* b2 = (const float*)d_in[6];
  const float* g2 = (const float*)d_in[7];
  const float* be2 = (const float*)d_in[8];
  const float* w3 = (const float*)d_in[9];
  const float* b3 = (const float*)d_in[10];
  const float* gum = (const float*)d_in[11];
  const int* bidx = (const int*)d_in[12];
  const int* ridx = (const int*)d_in[13];
  const int* cidx = (const int*)d_in[14];
  float* out = (float*)d_out;

  // workspace layout (floats)
  float* ws = (float*)d_ws;
  float* A = ws;                       // 8*384*64 = 196608
  float* Bv = A + BN * FF;             // 196608
  unsigned short* Whg = (unsigned short*)(ws + 393216);  // 4096 ushort (8 KB)
  unsigned short* Wlg = Whg + 4096;                      // 4096 ushort (8 KB) -> ends at float 397312
  float* wcol = ws + 397312;           // 64
  float* cb = wcol + FF;               // 64
  float* gw = cb + FF;                 // 64
  float* cwsgw = gw + FF;              // 2
  float* L = ws + 397520;              // 8*192*383 = 588288
  (void)ws_size; (void)n_in; (void)in_sizes; (void)out_size;

  hipLaunchKernelGGL(prep_all, dim3(BN / 4 + 1), dim3(64), 0, stream,
                     nodes, w1, b1, w2, b2, g1, be1, g2, be2, w3, b3,
                     A, Bv, Whg, Wlg, wcol, cb, gw, cwsgw);
  hipLaunchKernelGGL(edge_mlp, dim3(NBLKE), dim3(256), 0, stream,
                     A, Bv, Whg, Wlg, wcol, cb, gw, cwsgw, bidx, ridx, cidx, L,
                     (float4*)out);
  hipLaunchKernelGGL(argmax_scatter, dim3((SS * BB * NSINK) / 4), dim3(256), 0, stream,
                     L, gum, out);
}

// Round 15
// 134.576 us; speedup vs baseline: 1.2425x; 1.0318x over previous
//
#include <hip/hip_runtime.h>
#include <math.h>
#include <stdint.h>

// Problem constants (static per reference)
#define BB 8
#define NN 384
#define FF 64
#define TT 192
#define NSRC 383          // T + TAU - 1
#define NSINK 192
#define SS 5
#define NEDGE 441600      // B * 55200
#define BN (BB * NN)      // 3072
#define TILE_E 256        // edges per block (4 waves x 64, lane <-> edge)
#define NBLKE (NEDGE / TILE_E)    // 1725 exactly
#define OUTV ((BB * NN * NN) / 4) // 294912 float4 to zero

typedef _Float16 half8 __attribute__((ext_vector_type(8)));
typedef __fp16 fp16x2 __attribute__((ext_vector_type(2)));
typedef float floatx4 __attribute__((ext_vector_type(4)));

// 2-limb f16 split (prep side, RNE): x ~= h + l/512
static __device__ __forceinline__ void split_f16(float x, uint16_t& h, uint16_t& l) {
  const _Float16 hh = (_Float16)x;
  const float hb = (float)hh;
  const _Float16 ll = (_Float16)((x - hb) * 512.f);
  h = __builtin_bit_cast(uint16_t, hh);
  l = __builtin_bit_cast(uint16_t, ll);
}

// pair split via v_cvt_pkrtz (RTZ hi; residual captured exactly by the lo limb)
static __device__ __forceinline__ void split_pair(float x0, float x1,
                                                  uint32_t& hi, uint32_t& lo) {
  const fp16x2 h = __builtin_amdgcn_cvt_pkrtz(x0, x1);
  const float hb0 = (float)h.x, hb1 = (float)h.y;
  const fp16x2 l = __builtin_amdgcn_cvt_pkrtz((x0 - hb0) * 512.f, (x1 - hb1) * 512.f);
  hi = __builtin_bit_cast(uint32_t, h);
  lo = __builtin_bit_cast(uint32_t, l);
}

// ---------------- prep: node projections + weight folding + W f16-limb frags ----------------
// W frag slab (A-operand layout, per limb): ushort idx = (((jt*2+kc)*4+q)*16 + m)*8 + jj
//   <-> W[k = 32*kc + 8*q + jj][j = 16*jt + m]   (g1-folded weight)
__global__ __launch_bounds__(64) void prep_all(
    const float* __restrict__ nodes, const float* __restrict__ w1,
    const float* __restrict__ b1,
    const float* __restrict__ w2, const float* __restrict__ b2,
    const float* __restrict__ g1, const float* __restrict__ be1,
    const float* __restrict__ g2, const float* __restrict__ be2,
    const float* __restrict__ w3, const float* __restrict__ b3,
    float* __restrict__ A, float* __restrict__ Bv,
    unsigned short* __restrict__ Whg, unsigned short* __restrict__ Wlg,
    float* __restrict__ wcol, float* __restrict__ cb,
    float* __restrict__ gw, float* __restrict__ cwsgw) {
  const int blk = blockIdx.x;
  const int k = threadIdx.x;
  if (blk < BN / 4) {
    const int bn0 = blk * 4;
    __shared__ float nd[4][FF];
#pragma unroll
    for (int i = 0; i < 4; ++i) nd[i][k] = nodes[(bn0 + i) * FF + k];
    __syncthreads();
    const float bk = b1[k];
    float a0 = bk, a1 = bk, a2 = bk, a3 = bk;
    float q0 = 0.f, q1 = 0.f, q2 = 0.f, q3 = 0.f;
#pragma unroll 8
    for (int f = 0; f < FF; ++f) {
      const float wt = w1[f * FF + k];
      const float wb = w1[(FF + f) * FF + k];
      const float n0 = nd[0][f], n1 = nd[1][f], n2 = nd[2][f], n3 = nd[3][f];
      a0 = fmaf(n0, wt, a0); a1 = fmaf(n1, wt, a1);
      a2 = fmaf(n2, wt, a2); a3 = fmaf(n3, wt, a3);
      q0 = fmaf(n0, wb, q0); q1 = fmaf(n1, wb, q1);
      q2 = fmaf(n2, wb, q2); q3 = fmaf(n3, wb, q3);
    }
    A[(bn0 + 0) * FF + k] = a0;  Bv[(bn0 + 0) * FF + k] = q0;
    A[(bn0 + 1) * FF + k] = a1;  Bv[(bn0 + 1) * FF + k] = q1;
    A[(bn0 + 2) * FF + k] = a2;  Bv[(bn0 + 2) * FF + k] = q2;
    A[(bn0 + 3) * FF + k] = a3;  Bv[(bn0 + 3) * FF + k] = q3;
  } else {
    const int j = k;
    const int jt = j >> 4, m = j & 15;
    float cbj = b2[j];
    float wc = 0.f;
    for (int kk = 0; kk < FF; ++kk) {
      const float wraw = w2[kk * FF + j];
      const float w = g1[kk] * wraw;
      wc += w;
      cbj = fmaf(be1[kk], wraw, cbj);
      uint16_t hu, lu;
      split_f16(w, hu, lu);
      const int kc = kk >> 5, qq = (kk >> 3) & 3, jj = kk & 7;
      const int idx = (((jt * 2 + kc) * 4 + qq) * 16 + m) * 8 + jj;
      Whg[idx] = hu;
      Wlg[idx] = lu;
    }
    wcol[j] = wc;
    cb[j] = cbj;
    const float gwj = g2[j] * w3[j];
    gw[j] = gwj;
    __shared__ float sA[FF], sB[FF];
    sA[j] = gwj;
    sB[j] = be2[j] * w3[j];
    __syncthreads();
    if (j == 0) {
      float a = 0.f, bq = 0.f;
      for (int i = 0; i < FF; ++i) { a += sA[i]; bq += sB[i]; }
      cwsgw[0] = b3[0] + bq;
      cwsgw[1] = a;
    }
  }
}

// ---------------- main: MFMA edge MLP; W frags in registers, X limbs in LDS ----------------
// 256 thr = 4 waves, wave owns 64 edges (local edge = lane).
// mfma_f32_16x16x32_f16: A[m=lane&15][k=8*(lane>>4)+jj]; D col=lane&15, row=4*(lane>>4)+reg.
__global__ __launch_bounds__(256, 2) void edge_mlp(
    const float* __restrict__ A, const float* __restrict__ Bv,
    const unsigned short* __restrict__ Whg, const unsigned short* __restrict__ Wlg,
    const float* __restrict__ wcolg, const float* __restrict__ cbg,
    const float* __restrict__ gwg, const float* __restrict__ cwsgw,
    const int* __restrict__ bidx, const int* __restrict__ ridx,
    const int* __restrict__ cidx, float* __restrict__ L,
    float4* __restrict__ outv) {
  __shared__ __align__(16) unsigned short XHs[16384];   // 32 KB  X hi frags (4 waves)
  __shared__ __align__(16) unsigned short XLs[16384];   // 32 KB  X lo frags

  const int tid = threadIdx.x;       // 0..255
  const int wave = tid >> 6;
  const int lane = tid & 63;
  const int q4 = lane >> 4;          // quad
  const int c15 = lane & 15;

  // fused zeroing of the output grid
  const int gtid = blockIdx.x * 256 + tid;
  if (gtid < OUTV) outv[gtid] = make_float4(0.f, 0.f, 0.f, 0.f);

  // ---- hoist W frags into registers (16 KB table, L1-hot across blocks) ----
  half8 whr[4][2], wlr[4][2];
#pragma unroll
  for (int jt = 0; jt < 4; ++jt)
#pragma unroll
    for (int kc = 0; kc < 2; ++kc) {
      const int woff = ((jt * 2 + kc) * 4 + q4) * 128 + c15 * 8;
      whr[jt][kc] = *(const half8*)&Whg[woff];
      wlr[jt][kc] = *(const half8*)&Wlg[woff];
    }

  // ---- phase 1: lane <-> edge; gather, relu, stats, pkrtz-split into B-frag layout ----
  const int ge = blockIdx.x * TILE_E + tid;
  const int b = bidx[ge], r = ridx[ge], c = cidx[ge];
  const int et_own = lane >> 4, n_own = lane & 15;
  float mu, rstd;
  {
    const float4* pa = (const float4*)(A + (b * NN + r) * FF);
    const float4* pb = (const float4*)(Bv + (b * NN + c) * FF);
    unsigned short* dh = &XHs[wave * 4096 + n_own * 8];
    unsigned short* dl = &XLs[wave * 4096 + n_own * 8];
    float s = 0.f, q = 0.f;
#pragma unroll
    for (int g = 0; g < 8; ++g) {     // g -> k in [8g, 8g+8): kc=g>>2, q=g&3
      const float4 av0 = pa[2 * g], av1 = pa[2 * g + 1];
      const float4 bv0 = pb[2 * g], bv1 = pb[2 * g + 1];
      const float x0 = fmaxf(av0.x + bv0.x, 0.f);
      const float x1 = fmaxf(av0.y + bv0.y, 0.f);
      const float x2 = fmaxf(av0.z + bv0.z, 0.f);
      const float x3 = fmaxf(av0.w + bv0.w, 0.f);
      const float x4 = fmaxf(av1.x + bv1.x, 0.f);
      const float x5 = fmaxf(av1.y + bv1.y, 0.f);
      const float x6 = fmaxf(av1.z + bv1.z, 0.f);
      const float x7 = fmaxf(av1.w + bv1.w, 0.f);
      s += x0 + x1 + x2 + x3 + x4 + x5 + x6 + x7;
      q = fmaf(x0, x0, q); q = fmaf(x1, x1, q);
      q = fmaf(x2, x2, q); q = fmaf(x3, x3, q);
      q = fmaf(x4, x4, q); q = fmaf(x5, x5, q);
      q = fmaf(x6, x6, q); q = fmaf(x7, x7, q);
      int4 hi4, lo4;
      split_pair(x0, x1, *(uint32_t*)&hi4.x, *(uint32_t*)&lo4.x);
      split_pair(x2, x3, *(uint32_t*)&hi4.y, *(uint32_t*)&lo4.y);
      split_pair(x4, x5, *(uint32_t*)&hi4.z, *(uint32_t*)&lo4.z);
      split_pair(x6, x7, *(uint32_t*)&hi4.w, *(uint32_t*)&lo4.w);
      const int choff = ((et_own * 2 + (g >> 2)) * 4 + (g & 3)) * 128;
      *(int4*)(dh + choff) = hi4;
      *(int4*)(dl + choff) = lo4;
    }
    mu = s * (1.f / FF);
    rstd = 1.f / sqrtf(q * (1.f / FF) - mu * mu + 1e-5f);
  }

  __syncthreads();   // all X slabs visible

  // ---- per-lane j-constants: j = 16*jt + 4*q4 + reg ----
  floatx4 wc4[4], cb4[4], gw4[4];
#pragma unroll
  for (int jt = 0; jt < 4; ++jt) {
    wc4[jt] = *(const floatx4*)(wcolg + 16 * jt + 4 * q4);
    cb4[jt] = *(const floatx4*)(cbg + 16 * jt + 4 * q4);
    gw4[jt] = *(const floatx4*)(gwg + 16 * jt + 4 * q4);
  }
  const float cw = cwsgw[0], sgw = cwsgw[1];

  // ---- phase 2: MFMA K-loops + per-et epilogue ----
#pragma unroll
  for (int et = 0; et < 4; ++et) {
    floatx4 acc0[4], acc1[4];
#pragma unroll
    for (int jt = 0; jt < 4; ++jt) {
      acc0[jt] = (floatx4){0.f, 0.f, 0.f, 0.f};
      acc1[jt] = (floatx4){0.f, 0.f, 0.f, 0.f};
    }
#pragma unroll
    for (int kc = 0; kc < 2; ++kc) {
      const int xoff = wave * 4096 + ((et * 2 + kc) * 4 + q4) * 128 + c15 * 8;
      const half8 xh = *(const half8*)&XHs[xoff];
      const half8 xl = *(const half8*)&XLs[xoff];
#pragma unroll
      for (int jt = 0; jt < 4; ++jt) {
        acc0[jt] = __builtin_amdgcn_mfma_f32_16x16x32_f16(whr[jt][kc], xh, acc0[jt], 0, 0, 0);
        acc1[jt] = __builtin_amdgcn_mfma_f32_16x16x32_f16(whr[jt][kc], xl, acc1[jt], 0, 0, 0);
        acc1[jt] = __builtin_amdgcn_mfma_f32_16x16x32_f16(wlr[jt][kc], xh, acc1[jt], 0, 0, 0);
      }
    }
    // ---- epilogue for edges e2 = 16*et + c15 ----
    const int e2 = 16 * et + c15;
    const float mue = __shfl(mu, e2, 64);
    const float rse = __shfl(rstd, e2, 64);
    float s1 = 0.f, s2 = 0.f, s3 = 0.f;
#pragma unroll
    for (int jt = 0; jt < 4; ++jt) {
      const floatx4 t4 = acc0[jt] + acc1[jt] * (1.f / 512.f);
#pragma unroll
      for (int rg = 0; rg < 4; ++rg) {
        const float pre = fmaf(rse, fmaf(-mue, wc4[jt][rg], t4[rg]), cb4[jt][rg]);
        const float tr = fmaxf(pre, 0.f);
        s1 += tr;
        s2 = fmaf(tr, tr, s2);
        s3 = fmaf(tr, gw4[jt][rg], s3);
      }
    }
    // sum over the 4 quads (disjoint 16-j subsets)
    s1 += __shfl_xor(s1, 16, 64); s1 += __shfl_xor(s1, 32, 64);
    s2 += __shfl_xor(s2, 16, 64); s2 += __shfl_xor(s2, 32, 64);
    s3 += __shfl_xor(s3, 16, 64); s3 += __shfl_xor(s3, 32, 64);
    // b/r/c of edge e2 live in lane e2 of this wave
    const int b2 = __shfl(b, e2, 64);
    const int r2 = __shfl(r, e2, 64);
    const int c2 = __shfl(c, e2, 64);
    if (q4 == 0) {
      const float mu2 = s1 * (1.f / FF);
      const float var2 = s2 * (1.f / FF) - mu2 * mu2;
      const float rstd2 = 1.f / sqrtf(var2 + 1e-5f);
      const float logit = fmaf(rstd2, fmaf(-mu2, sgw, s3), cw);
      L[(b2 * NSINK + (r2 - TT)) * NSRC + c2] = logit;
    }
  }
}

// ---------------- argmax over sources + scatter ones ----------------
__global__ __launch_bounds__(256) void argmax_scatter(
    const float* __restrict__ L, const float* __restrict__ gum,
    float* __restrict__ out) {
  const int task = blockIdx.x * 4 + (threadIdx.x >> 6);  // ((s*B+b)*192+row)
  const int lane = threadIdx.x & 63;
  const int row = task % NSINK;
  const int sb = task / NSINK;   // s*B + b
  const int b = sb & 7;
  const int r = row + TT;

  const float* __restrict__ lrow = L + (b * NSINK + row) * NSRC;
  const float* __restrict__ grow = gum + task * NSRC;

  float bv = -INFINITY;
  int bi = 0;
  for (int c = lane; c < r; c += 64) {
    const float v = lrow[c] + grow[c];
    if (v > bv) { bv = v; bi = c; }   // strict > keeps smallest index per lane
  }
#pragma unroll
  for (int off = 32; off > 0; off >>= 1) {
    const float ov = __shfl_xor(bv, off, 64);
    const int oi = __shfl_xor(bi, off, 64);
    if (ov > bv || (ov == bv && oi < bi)) { bv = ov; bi = oi; }
  }
  if (lane == 0) out[(b * NN + r) * NN + bi] = 1.0f;
}

extern "C" void kernel_launch(void* const* d_in, const int* in_sizes, int n_in,
                              void* d_out, int out_size, void* d_ws, size_t ws_size,
                              hipStream_t stream) {
  const float* nodes = (const float*)d_in[0];
  const float* w1 = (const float*)d_in[1];
  const float* b1 = (const float*)d_in[2];
  const float* g1 = (const float*)d_in[3];
  const float* be1 = (const float*)d_in[4];
  const float* w2 = (const float*)d_in[5];
  const float* b2 = (const float*)d_in[6];
  const float* g2 = (const float*)d_in[7];
  const float* be2 = (const float*)d_in[8];
  const float* w3 = (const float*)d_in[9];
  const float* b3 = (const float*)d_in[10];
  const float* gum = (const float*)d_in[11];
  const int* bidx = (const int*)d_in[12];
  const int* ridx = (const int*)d_in[13];
  const int* cidx = (const int*)d_in[14];
  float* out = (float*)d_out;

  // workspace layout (floats)
  float* ws = (float*)d_ws;
  float* A = ws;                       // 8*384*64 = 196608
  float* Bv = A + BN * FF;             // 196608
  unsigned short* Whg = (unsigned short*)(ws + 393216);  // 4096 ushort (8 KB)
  unsigned short* Wlg = Whg + 4096;                      // 4096 ushort -> ends at float 397312
  float* wcol = ws + 397312;           // 64
  float* cb = wcol + FF;               // 64
  float* gw = cb + FF;                 // 64
  float* cwsgw = gw + FF;              // 2
  float* L = ws + 397520;              // 8*192*383 = 588288
  (void)ws_size; (void)n_in; (void)in_sizes; (void)out_size;

  hipLaunchKernelGGL(prep_all, dim3(BN / 4 + 1), dim3(64), 0, stream,
                     nodes, w1, b1, w2, b2, g1, be1, g2, be2, w3, b3,
                     A, Bv, Whg, Wlg, wcol, cb, gw, cwsgw);
  hipLaunchKernelGGL(edge_mlp, dim3(NBLKE), dim3(256), 0, stream,
                     A, Bv, Whg, Wlg, wcol, cb, gw, cwsgw, bidx, ridx, cidx, L,
                     (float4*)out);
  hipLaunchKernelGGL(argmax_scatter, dim3((SS * BB * NSINK) / 4), dim3(256), 0, stream,
                     L, gum, out);
}